// Round 15
// baseline (556.996 us; speedup 1.0000x reference)
//
#include <hip/hip_runtime.h>
#include <hip/hip_bf16.h>

typedef __hip_bfloat16 bf16;

// Problem constants
constexpr int Bc  = 8;
constexpr int Lc  = 2500;
constexpr int Cc  = 14;
constexpr int Kc  = 9;
constexpr int Nn  = Bc * Lc;     // 20000
constexpr int NCLS = 20;
constexpr int HID = 128;
constexpr int NL  = 3;
constexpr int CC  = Cc * Cc;     // 196
constexpr int X3  = Cc * 3;      // 42

typedef __bf16 bf16x8 __attribute__((ext_vector_type(8)));
typedef short  sh8    __attribute__((ext_vector_type(8)));
typedef float  f32x4  __attribute__((ext_vector_type(4)));

__device__ __forceinline__ float b2f(bf16 x) { return __bfloat162float(x); }
__device__ __forceinline__ float b2fu(unsigned short u) {
  return __uint_as_float(((unsigned int)u) << 16);
}
__device__ __forceinline__ unsigned short f2bu(float x) {
  bf16 h = __float2bfloat16(x);
  return *reinterpret_cast<unsigned short*>(&h);
}
// fast silu: v_exp-based expf + v_rcp (no full-precision divide)
__device__ __forceinline__ float siluf(float x) {
  return x * __builtin_amdgcn_rcpf(1.0f + __expf(-x));
}
__device__ __forceinline__ int clampi(int v, int n) {
  return ((unsigned)v < (unsigned)n) ? v : 0;
}
__device__ __forceinline__ void unpk2(unsigned int u, float& a, float& b) {
  a = __uint_as_float(u << 16);
  b = __uint_as_float(u & 0xffff0000u);
}

__device__ __forceinline__ f32x4 mfma16(sh8 a, sh8 b, f32x4 c) {
  return __builtin_amdgcn_mfma_f32_16x16x32_bf16(
      __builtin_bit_cast(bf16x8, a), __builtin_bit_cast(bf16x8, b), c, 0, 0, 0);
}

// A/activation fragment-linear offset (in shorts). MT m-tiles; tile = 512 shorts.
__device__ __forceinline__ int fragoff(int e, int k, int MT) {
  return (((k >> 5) * MT + (e >> 4)) << 9) +
         (((e & 15) + (((k >> 3) & 3) << 4)) << 3) + (k & 7);
}

// ---------------------------------------------------------------------------
// Wrp[l] = Wr[l] @ We1[l][256:384,:] with c-aligned 256-row padding:
//   row m<126: c=m/14,d=m%14; 128<=m<198: c=9+(m-128)/14; else zero.
// ---------------------------------------------------------------------------
__global__ __launch_bounds__(128) void wrp_kernel(const float* __restrict__ Wr,
                                                  const float* __restrict__ We1,
                                                  float* __restrict__ Wrp) {
  int l = blockIdx.x >> 8, m = blockIdx.x & 255;
  int t = threadIdx.x;
  int c = 0, d = 0;
  bool real = false;
  if (m < 126) { c = m / 14; d = m - c * 14; real = true; }
  else if (m >= 128 && m < 198) {
    int mm = m - 128;
    c = 9 + mm / 14; d = mm - (mm / 14) * 14; real = true;
  }
  if (!real) { Wrp[(size_t)(l * 256 + m) * HID + t] = 0.f; return; }
  int j = c * Cc + d;
  __shared__ float row[HID];
  row[t] = Wr[(size_t)(l * CC + j) * HID + t];
  __syncthreads();
  float acc = 0.f;
  #pragma unroll 4
  for (int k = 0; k < HID; ++k)
    acc += row[k] * We1[(size_t)(l * 384 + 256 + k) * HID + t];
  Wrp[(size_t)(l * 256 + m) * HID + t] = acc;
}

// ---------------------------------------------------------------------------
// Batched weight shuffle: fp32 KxN -> B-fragment-linear bf16 (zero-padded).
// ---------------------------------------------------------------------------
constexpr int NSH = 26;
struct ShufArgs {
  const float* src[NSH];
  unsigned short* dst[NSH];
  int K[NSH], N[NSH], KT[NSH], NT[NSH];
};

__global__ void shufb_kernel(ShufArgs a) {
  int e = blockIdx.y;
  int K = a.K[e], N = a.N[e], NT = a.NT[e];
  int total = a.KT[e] * NT * 512;
  const float* W = a.src[e];
  unsigned short* out = a.dst[e];
  for (int idx = blockIdx.x * blockDim.x + threadIdx.x; idx < total;
       idx += gridDim.x * blockDim.x) {
    int j = idx & 7;
    int lane = (idx >> 3) & 63;
    int nt = (idx >> 9) % NT;
    int kt = idx / (512 * NT);
    int k = kt * 32 + ((lane >> 4) << 3) + j;
    int n = nt * 16 + (lane & 15);
    float v = (k < K && n < N) ? W[(size_t)k * N + n] : 0.f;
    out[idx] = f2bu(v);
  }
}

// Htab = E_tab @ Win (20x128); cwtab = row-softmax(Wchan) (20x14)
__global__ __launch_bounds__(128) void htab_kernel(const float* __restrict__ Et,
                                                   const float* __restrict__ Win,
                                                   const float* __restrict__ Wch,
                                                   float* __restrict__ Htab,
                                                   float* __restrict__ cwtab) {
  int r = blockIdx.x, t = threadIdx.x;
  __shared__ float e[HID];
  e[t] = Et[r * HID + t];
  __syncthreads();
  float acc = 0.f;
  #pragma unroll 4
  for (int k = 0; k < HID; ++k) acc += e[k] * Win[k * HID + t];
  Htab[r * HID + t] = acc;
  if (t == 0) {
    float v[Cc];
    float mx = -1e30f;
    for (int c = 0; c < Cc; ++c) { v[c] = Wch[r * Cc + c]; mx = fmaxf(mx, v[c]); }
    float s = 0.f;
    for (int c = 0; c < Cc; ++c) { v[c] = __expf(v[c] - mx); s += v[c]; }
    float inv = 1.0f / s;
    for (int c = 0; c < Cc; ++c) cwtab[r * Cc + c] = v[c] * inv;
  }
}

// ---------------------------------------------------------------------------
// Extract CA coords to compact global SoA: posG[comp][axis][PSTR]
// ---------------------------------------------------------------------------
constexpr int PSTR = 2512;

__global__ void posx_kernel(const float* __restrict__ X, float* __restrict__ posG) {
  int total = Bc * PSTR;
  for (int i = blockIdx.x * blockDim.x + threadIdx.x; i < total;
       i += gridDim.x * blockDim.x) {
    int comp = i / PSTR, j = i - comp * PSTR;
    float x = 1e30f, y = 1e30f, z = 1e30f;
    if (j < Lc) {
      size_t g = (size_t)(comp * Lc + j) * X3;
      x = X[g + 3]; y = X[g + 4]; z = X[g + 5];
    }
    float* b = posG + (size_t)comp * 3 * PSTR;
    b[j] = x; b[PSTR + j] = y; b[2 * PSTR + j] = z;
  }
}

// ---------------------------------------------------------------------------
// kNN, zero-LDS: 4 rows/block, 64 threads/row, 40 candidates/thread.
// 64-bit shfl_xor min-reduction over the full wave merges the 64 sorted
// top-9 lists; key (d2_bits<<32)|idx gives exact jax top_k stable order.
// ---------------------------------------------------------------------------
constexpr int KR2 = 4;
constexpr int KC2 = 40;

__global__ __launch_bounds__(256) void knn_kernel(const float* __restrict__ posG,
                                                  int* __restrict__ nbr) {
  constexpr int bpc = (Lc + KR2 - 1) / KR2;   // 625
  int comp = blockIdx.x / bpc, rb = blockIdx.x % bpc;
  int t = threadIdx.x;
  int rl = t >> 6, q = t & 63;
  int r = rb * KR2 + rl;
  const float* px = posG + (size_t)comp * 3 * PSTR;
  const float* py = px + PSTR;
  const float* pz = py + PSTR;

  float bd[Kc];
  int   bi[Kc];
  #pragma unroll
  for (int k = 0; k < Kc; ++k) { bd[k] = __int_as_float(0x7f800000); bi[k] = 0x7fffffff; }

  if (r < Lc) {
    float rx = px[r], ry = py[r], rz = pz[r];
    int c0 = q * KC2;
    int c1 = c0 + KC2; if (c1 > Lc) c1 = Lc;
    for (int i = c0; i < c1; i += 4) {
      float4 xs = *(const float4*)(px + i);
      float4 ys = *(const float4*)(py + i);
      float4 zs = *(const float4*)(pz + i);
      float d2v[4];
      {
        float dx, dy, dz;
        dx = rx - xs.x; dy = ry - ys.x; dz = rz - zs.x; d2v[0] = dx*dx + dy*dy + dz*dz;
        dx = rx - xs.y; dy = ry - ys.y; dz = rz - zs.y; d2v[1] = dx*dx + dy*dy + dz*dz;
        dx = rx - xs.z; dy = ry - ys.z; dz = rz - zs.z; d2v[2] = dx*dx + dy*dy + dz*dz;
        dx = rx - xs.w; dy = ry - ys.w; dz = rz - zs.w; d2v[3] = dx*dx + dy*dy + dz*dz;
      }
      #pragma unroll
      for (int u = 0; u < 4; ++u) {
        int ii = i + u;
        float d2 = d2v[u];
        if (ii != r && d2 < bd[Kc - 1]) {
          bd[Kc - 1] = d2; bi[Kc - 1] = ii;
          #pragma unroll
          for (int p = Kc - 1; p > 0; --p) {
            if (bd[p] < bd[p - 1]) {
              float td = bd[p]; bd[p] = bd[p - 1]; bd[p - 1] = td;
              int   ti = bi[p]; bi[p] = bi[p - 1]; bi[p - 1] = ti;
            }
          }
        }
      }
    }
  }

  int gbase = (comp * Lc + r) * Kc;
  #pragma unroll
  for (int k = 0; k < Kc; ++k) {
    unsigned long long mykey =
        ((unsigned long long)__float_as_uint(bd[0]) << 32) | (unsigned int)bi[0];
    unsigned long long w = mykey;
    #pragma unroll
    for (int m = 1; m <= 32; m <<= 1) {
      unsigned long long o = __shfl_xor(w, m);
      if (o < w) w = o;
    }
    if (r < Lc && q == k)
      nbr[gbase + k] = comp * Lc + (int)(unsigned int)(w & 0xffffffffULL);
    if (mykey == w) {
      #pragma unroll
      for (int s = 0; s < Kc - 1; ++s) { bd[s] = bd[s + 1]; bi[s] = bi[s + 1]; }
      bd[Kc - 1] = __int_as_float(0x7f800000); bi[Kc - 1] = 0x7fffffff;
    }
  }
}

// ---------------------------------------------------------------------------
// MFMA node AB (layer 0), with fused embedding gather
// ---------------------------------------------------------------------------
__global__ __launch_bounds__(256) void nodeABm_kernel(
    const int* __restrict__ S, const float* __restrict__ Htab,
    float* __restrict__ hv,
    const unsigned short* __restrict__ We1a_s, const unsigned short* __restrict__ We1b_s,
    const float* __restrict__ be1n, bf16* __restrict__ hA, bf16* __restrict__ hB) {
  __shared__ __align__(16) unsigned short sB[4 * 512];
  int t = threadIdx.x, n0 = blockIdx.x * 16;
  int lane = t & 63, wv = t >> 6, quad = lane >> 4, l15 = lane & 15, wnb = wv << 5;

  for (int o = t; o < 16 * HID; o += 256) {
    int row = o >> 7, k = o & 127;
    float v = Htab[clampi(S[n0 + row], NCLS) * HID + k];
    hv[(size_t)(n0 + row) * HID + k] = v;
    sB[fragoff(row, k, 1)] = f2bu(v);
  }
  __syncthreads();

  f32x4 a3[2] = {{0,0,0,0},{0,0,0,0}}, a4[2] = {{0,0,0,0},{0,0,0,0}};
  const sh8* sBv = (const sh8*)sB;
  for (int kt = 0; kt < 4; ++kt) {
    sh8 a = sBv[kt * 64 + lane];
    sh8 b0 = ((const sh8*)We1a_s)[((kt << 3) + (wv << 1) + 0) * 64 + lane];
    sh8 b1 = ((const sh8*)We1a_s)[((kt << 3) + (wv << 1) + 1) * 64 + lane];
    sh8 c0 = ((const sh8*)We1b_s)[((kt << 3) + (wv << 1) + 0) * 64 + lane];
    sh8 c1 = ((const sh8*)We1b_s)[((kt << 3) + (wv << 1) + 1) * 64 + lane];
    a3[0] = mfma16(a, b0, a3[0]); a3[1] = mfma16(a, b1, a3[1]);
    a4[0] = mfma16(a, c0, a4[0]); a4[1] = mfma16(a, c1, a4[1]);
  }
  #pragma unroll
  for (int nl = 0; nl < 2; ++nl) {
    int col = wnb + (nl << 4) + l15;
    float be = be1n[col];
    #pragma unroll
    for (int r = 0; r < 4; ++r) {
      int row = (quad << 2) + r;
      hA[(size_t)(n0 + row) * HID + col] = __float2bfloat16(a3[nl][r] + be);
      hB[(size_t)(n0 + row) * HID + col] = __float2bfloat16(a4[nl][r]);
    }
  }
}

// ---------------------------------------------------------------------------
// MFMA fused node update + next AB  (unchanged)
// ---------------------------------------------------------------------------
__global__ __launch_bounds__(256) void fupdAB_kernel(
    float* __restrict__ h, const bf16* __restrict__ aggm,
    const unsigned short* __restrict__ Wh1_s, const unsigned short* __restrict__ Wh2_s,
    const unsigned short* __restrict__ We1a_s, const unsigned short* __restrict__ We1b_s,
    const float* __restrict__ be1n, bf16* __restrict__ hA, bf16* __restrict__ hB) {
  __shared__ __align__(16) unsigned short sA[8 * 512];
  __shared__ __align__(16) unsigned short sB[4 * 512];
  int t = threadIdx.x, n0 = blockIdx.x * 16;
  int lane = t & 63, wv = t >> 6, quad = lane >> 4, l15 = lane & 15, wnb = wv << 5;

  for (int o = t; o < 16 * 256; o += 256) {
    int row = o >> 8, k = o & 255;
    float v = (k < HID) ? h[(size_t)(n0 + row) * HID + k]
                        : b2f(aggm[(size_t)(n0 + row) * HID + (k - HID)]);
    sA[fragoff(row, k, 1)] = f2bu(v);
  }
  __syncthreads();

  f32x4 a1[2] = {{0,0,0,0},{0,0,0,0}};
  const sh8* sAv = (const sh8*)sA;
  for (int kt = 0; kt < 8; ++kt) {
    sh8 a = sAv[kt * 64 + lane];
    sh8 b0 = ((const sh8*)Wh1_s)[((kt << 3) + (wv << 1) + 0) * 64 + lane];
    sh8 b1 = ((const sh8*)Wh1_s)[((kt << 3) + (wv << 1) + 1) * 64 + lane];
    a1[0] = mfma16(a, b0, a1[0]);
    a1[1] = mfma16(a, b1, a1[1]);
  }
  #pragma unroll
  for (int nl = 0; nl < 2; ++nl) {
    int col = wnb + (nl << 4) + l15;
    #pragma unroll
    for (int r = 0; r < 4; ++r)
      sB[fragoff((quad << 2) + r, col, 1)] = f2bu(siluf(a1[nl][r]));
  }
  __syncthreads();

  f32x4 a2[2] = {{0,0,0,0},{0,0,0,0}};
  const sh8* sBv = (const sh8*)sB;
  for (int kt = 0; kt < 4; ++kt) {
    sh8 a = sBv[kt * 64 + lane];
    sh8 b0 = ((const sh8*)Wh2_s)[((kt << 3) + (wv << 1) + 0) * 64 + lane];
    sh8 b1 = ((const sh8*)Wh2_s)[((kt << 3) + (wv << 1) + 1) * 64 + lane];
    a2[0] = mfma16(a, b0, a2[0]);
    a2[1] = mfma16(a, b1, a2[1]);
  }
  float hn[2][4];
  #pragma unroll
  for (int nl = 0; nl < 2; ++nl) {
    int col = wnb + (nl << 4) + l15;
    #pragma unroll
    for (int r = 0; r < 4; ++r) {
      int row = (quad << 2) + r;
      float v = h[(size_t)(n0 + row) * HID + col] + a2[nl][r];
      h[(size_t)(n0 + row) * HID + col] = v;
      hn[nl][r] = v;
    }
  }
  __syncthreads();
  #pragma unroll
  for (int nl = 0; nl < 2; ++nl) {
    int col = wnb + (nl << 4) + l15;
    #pragma unroll
    for (int r = 0; r < 4; ++r)
      sB[fragoff((quad << 2) + r, col, 1)] = f2bu(hn[nl][r]);
  }
  __syncthreads();

  f32x4 a3[2] = {{0,0,0,0},{0,0,0,0}}, a4[2] = {{0,0,0,0},{0,0,0,0}};
  for (int kt = 0; kt < 4; ++kt) {
    sh8 a = sBv[kt * 64 + lane];
    sh8 b0 = ((const sh8*)We1a_s)[((kt << 3) + (wv << 1) + 0) * 64 + lane];
    sh8 b1 = ((const sh8*)We1a_s)[((kt << 3) + (wv << 1) + 1) * 64 + lane];
    sh8 c0 = ((const sh8*)We1b_s)[((kt << 3) + (wv << 1) + 0) * 64 + lane];
    sh8 c1 = ((const sh8*)We1b_s)[((kt << 3) + (wv << 1) + 1) * 64 + lane];
    a3[0] = mfma16(a, b0, a3[0]); a3[1] = mfma16(a, b1, a3[1]);
    a4[0] = mfma16(a, c0, a4[0]); a4[1] = mfma16(a, c1, a4[1]);
  }
  #pragma unroll
  for (int nl = 0; nl < 2; ++nl) {
    int col = wnb + (nl << 4) + l15;
    float be = be1n[col];
    #pragma unroll
    for (int r = 0; r < 4; ++r) {
      int row = (quad << 2) + r;
      hA[(size_t)(n0 + row) * HID + col] = __float2bfloat16(a3[nl][r] + be);
      hB[(size_t)(n0 + row) * HID + col] = __float2bfloat16(a4[nl][r]);
    }
  }
}

// ---------------------------------------------------------------------------
// MFMA fused last node update + final FFN  (unchanged)
// ---------------------------------------------------------------------------
__global__ __launch_bounds__(256) void fupdF_kernel(
    const float* __restrict__ h, const bf16* __restrict__ aggm,
    const unsigned short* __restrict__ Wh1_s, const unsigned short* __restrict__ Wh2_s,
    const unsigned short* __restrict__ Wf1_s, const unsigned short* __restrict__ Wf2_s,
    float* __restrict__ out) {
  __shared__ __align__(16) unsigned short sA[8 * 512];
  __shared__ __align__(16) unsigned short sB[4 * 512];
  int t = threadIdx.x, n0 = blockIdx.x * 16;
  int lane = t & 63, wv = t >> 6, quad = lane >> 4, l15 = lane & 15, wnb = wv << 5;

  for (int o = t; o < 16 * 256; o += 256) {
    int row = o >> 8, k = o & 255;
    float v = (k < HID) ? h[(size_t)(n0 + row) * HID + k]
                        : b2f(aggm[(size_t)(n0 + row) * HID + (k - HID)]);
    sA[fragoff(row, k, 1)] = f2bu(v);
  }
  __syncthreads();

  f32x4 a1[2] = {{0,0,0,0},{0,0,0,0}};
  const sh8* sAv = (const sh8*)sA;
  for (int kt = 0; kt < 8; ++kt) {
    sh8 a = sAv[kt * 64 + lane];
    sh8 b0 = ((const sh8*)Wh1_s)[((kt << 3) + (wv << 1) + 0) * 64 + lane];
    sh8 b1 = ((const sh8*)Wh1_s)[((kt << 3) + (wv << 1) + 1) * 64 + lane];
    a1[0] = mfma16(a, b0, a1[0]);
    a1[1] = mfma16(a, b1, a1[1]);
  }
  #pragma unroll
  for (int nl = 0; nl < 2; ++nl) {
    int col = wnb + (nl << 4) + l15;
    #pragma unroll
    for (int r = 0; r < 4; ++r)
      sB[fragoff((quad << 2) + r, col, 1)] = f2bu(siluf(a1[nl][r]));
  }
  __syncthreads();

  f32x4 a2[2] = {{0,0,0,0},{0,0,0,0}};
  const sh8* sBv = (const sh8*)sB;
  for (int kt = 0; kt < 4; ++kt) {
    sh8 a = sBv[kt * 64 + lane];
    sh8 b0 = ((const sh8*)Wh2_s)[((kt << 3) + (wv << 1) + 0) * 64 + lane];
    sh8 b1 = ((const sh8*)Wh2_s)[((kt << 3) + (wv << 1) + 1) * 64 + lane];
    a2[0] = mfma16(a, b0, a2[0]);
    a2[1] = mfma16(a, b1, a2[1]);
  }
  float u2[2][4];
  #pragma unroll
  for (int nl = 0; nl < 2; ++nl) {
    int col = wnb + (nl << 4) + l15;
    #pragma unroll
    for (int r = 0; r < 4; ++r) {
      int row = (quad << 2) + r;
      u2[nl][r] = siluf(h[(size_t)(n0 + row) * HID + col] + a2[nl][r]);
    }
  }
  __syncthreads();
  #pragma unroll
  for (int nl = 0; nl < 2; ++nl) {
    int col = wnb + (nl << 4) + l15;
    #pragma unroll
    for (int r = 0; r < 4; ++r)
      sB[fragoff((quad << 2) + r, col, 1)] = f2bu(u2[nl][r]);
  }
  __syncthreads();

  f32x4 a3[2] = {{0,0,0,0},{0,0,0,0}};
  for (int kt = 0; kt < 4; ++kt) {
    sh8 a = sBv[kt * 64 + lane];
    sh8 b0 = ((const sh8*)Wf1_s)[((kt << 3) + (wv << 1) + 0) * 64 + lane];
    sh8 b1 = ((const sh8*)Wf1_s)[((kt << 3) + (wv << 1) + 1) * 64 + lane];
    a3[0] = mfma16(a, b0, a3[0]);
    a3[1] = mfma16(a, b1, a3[1]);
  }
  #pragma unroll
  for (int nl = 0; nl < 2; ++nl) {
    int col = wnb + (nl << 4) + l15;
    #pragma unroll
    for (int r = 0; r < 4; ++r)
      sA[fragoff((quad << 2) + r, col, 1)] = f2bu(siluf(a3[nl][r]));
  }
  __syncthreads();

  if (wv < 2) {
    f32x4 a5 = {0.f, 0.f, 0.f, 0.f};
    for (int kt = 0; kt < 4; ++kt) {
      sh8 a = sAv[kt * 64 + lane];
      sh8 b = ((const sh8*)Wf2_s)[(kt * 2 + wv) * 64 + lane];
      a5 = mfma16(a, b, a5);
    }
    int col = (wv << 4) + l15;
    if (col < NCLS) {
      #pragma unroll
      for (int r = 0; r < 4; ++r) {
        int row = (quad << 2) + r;
        out[(size_t)(n0 + row) * NCLS + col] = a5[r];
      }
    }
  }
}

// ---------------------------------------------------------------------------
// MFMA edge kernel — stage-1 K split into two passes over one 48x128 buffer
// (c-aligned padded rad space, K=256); LDS ~29.2 KB -> 5 blocks/CU.
// ---------------------------------------------------------------------------
constexpr int GN  = 4;
constexpr int NE  = GN * Kc;     // 36
constexpr int MT3 = 3;           // m-tiles (M padded to 48)

__global__ __launch_bounds__(256) void edge_kernel(
    const float* __restrict__ Xin, float* __restrict__ Xout,
    const bf16* __restrict__ hA, const bf16* __restrict__ hB,
    const int* __restrict__ S, const float* __restrict__ cwtab,
    const int* __restrict__ nbr,
    const unsigned short* __restrict__ Wrp_s, const unsigned short* __restrict__ We2_s,
    const unsigned short* __restrict__ Wx1_s, const unsigned short* __restrict__ Wx2_s,
    bf16* __restrict__ aggm) {
  __shared__ __align__(16) unsigned short s_R1[48 * 128];  // 12288 B
  __shared__ __align__(16) unsigned short s_R2[48 * 128];  // 12288 B
  __shared__ __align__(16) unsigned short s_xd[NE * 44];   //  3168 B
  __shared__ __align__(16) unsigned short s_hA[GN * 128];  //  1024 B
  __shared__ float s_cw[GN * Cc];
  __shared__ int   s_dst[NE];

  int t = threadIdx.x;
  int n0 = blockIdx.x * GN;
  int lane = t & 63, wv = t >> 6;
  int quad = lane >> 4, l15 = lane & 15;
  int wnb = wv << 5;

  if (t < NE) s_dst[t] = clampi(nbr[n0 * Kc + t], Nn);
  if (t >= 64 && t < 64 + GN * Cc) {
    int o = t - 64;
    s_cw[o] = cwtab[clampi(S[n0 + o / Cc], NCLS) * Cc + o % Cc];
  }
  {
    uint4* r1 = (uint4*)s_R1;
    for (int o = t; o < 768; o += 256) r1[o] = make_uint4(0u, 0u, 0u, 0u);
    uint4* r2 = (uint4*)s_R2;
    for (int o = t; o < 768; o += 256) r2[o] = make_uint4(0u, 0u, 0u, 0u);
    const unsigned int* src = (const unsigned int*)(hA + (size_t)n0 * HID);
    unsigned int* dA = (unsigned int*)s_hA;
    for (int o = t; o < GN * 64; o += 256) dA[o] = src[o];
  }
  __syncthreads();

  // prefetch hB fragments direct from global (latency hidden by stage-1 MFMA)
  unsigned short hbr[MT3][2][4];
  {
    const unsigned short* hbu = (const unsigned short*)hB;
    #pragma unroll
    for (int mt = 0; mt < MT3; ++mt)
      #pragma unroll
      for (int nl = 0; nl < 2; ++nl) {
        int col = wnb + (nl << 4) + l15;
        #pragma unroll
        for (int r = 0; r < 4; ++r) {
          int row = (mt << 4) + (quad << 2) + r;
          hbr[mt][nl][r] =
              (row < NE) ? hbu[(size_t)s_dst[row] * HID + col] : (unsigned short)0;
        }
      }
  }

  for (int o = t; o < NE * X3; o += 256) {
    int e = o / X3, i = o - e * X3;
    float v = Xin[(size_t)(n0 + e / Kc) * X3 + i] - Xin[(size_t)s_dst[e] * X3 + i];
    s_xd[e * 44 + i] = f2bu(v);
  }
  __syncthreads();

  // ---- pass A rad fill: cols m=c*14+d for c in [0,9); 180 items ----
  if (t < 180) {
    int e = t / 5, jc = t - (t / 5) * 5;
    const unsigned int* xu = (const unsigned int*)(s_xd + e * 44);
    unsigned int u[21];
    #pragma unroll
    for (int i = 0; i < 21; ++i) u[i] = xu[i];
    float xdv[42];
    #pragma unroll
    for (int i = 0; i < 21; ++i) unpk2(u[i], xdv[2 * i], xdv[2 * i + 1]);
    const unsigned short* xe = s_xd + e * 44;
    #pragma unroll
    for (int half = 0; half < 2; ++half) {
      int c = 2 * jc + half;
      if (c <= 8) {
        float xc0 = b2fu(xe[c * 3 + 0]);
        float xc1 = b2fu(xe[c * 3 + 1]);
        float xc2 = b2fu(xe[c * 3 + 2]);
        int jbase = c * Cc;
        #pragma unroll
        for (int d = 0; d < 14; ++d) {
          float v = (xc0 * xdv[d * 3 + 0] + xc1 * xdv[d * 3 + 1] +
                     xc2 * xdv[d * 3 + 2]) * (1.0f / 14.0f);
          s_R1[fragoff(e, jbase + d, MT3)] = f2bu(v);
        }
      }
    }
  }
  __syncthreads();

  // ---- stage 1 MFMA pass A (kt 0..3) ----
  f32x4 acc1[MT3][2];
  #pragma unroll
  for (int mt = 0; mt < MT3; ++mt)
    #pragma unroll
    for (int nl = 0; nl < 2; ++nl) acc1[mt][nl] = (f32x4){0.f, 0.f, 0.f, 0.f};
  const sh8* r1v = (const sh8*)s_R1;
  for (int kt = 0; kt < 4; ++kt) {
    sh8 b0 = ((const sh8*)Wrp_s)[((kt << 3) + (wv << 1) + 0) * 64 + lane];
    sh8 b1 = ((const sh8*)Wrp_s)[((kt << 3) + (wv << 1) + 1) * 64 + lane];
    #pragma unroll
    for (int mt = 0; mt < MT3; ++mt) {
      sh8 a = r1v[(kt * MT3 + mt) * 64 + lane];
      acc1[mt][0] = mfma16(a, b0, acc1[mt][0]);
      acc1[mt][1] = mfma16(a, b1, acc1[mt][1]);
    }
  }
  __syncthreads();   // pass-A reads done
  {
    uint4* r1z = (uint4*)s_R1;
    for (int o = t; o < 768; o += 256) r1z[o] = make_uint4(0u, 0u, 0u, 0u);
  }
  __syncthreads();

  // ---- pass B rad fill: local col (c-9)*14+d for c in [9,14); light regs ----
  for (int o = t; o < NE * Cc; o += 256) {   // 504 items: (e, d)
    int e = o / Cc, d = o - (o / Cc) * Cc;
    const unsigned short* xe = s_xd + e * 44;
    float xd0 = b2fu(xe[d * 3 + 0]);
    float xd1 = b2fu(xe[d * 3 + 1]);
    float xd2 = b2fu(xe[d * 3 + 2]);
    #pragma unroll
    for (int ci = 0; ci < 5; ++ci) {
      int c = 9 + ci;
      float v = (b2fu(xe[c * 3 + 0]) * xd0 + b2fu(xe[c * 3 + 1]) * xd1 +
                 b2fu(xe[c * 3 + 2]) * xd2) * (1.0f / 14.0f);
      s_R1[fragoff(e, ci * Cc + d, MT3)] = f2bu(v);
    }
  }
  __syncthreads();

  // ---- stage 1 MFMA pass B (kt 4..7) ----
  for (int kt = 4; kt < 8; ++kt) {
    sh8 b0 = ((const sh8*)Wrp_s)[((kt << 3) + (wv << 1) + 0) * 64 + lane];
    sh8 b1 = ((const sh8*)Wrp_s)[((kt << 3) + (wv << 1) + 1) * 64 + lane];
    #pragma unroll
    for (int mt = 0; mt < MT3; ++mt) {
      sh8 a = r1v[((kt - 4) * MT3 + mt) * 64 + lane];
      acc1[mt][0] = mfma16(a, b0, acc1[mt][0]);
      acc1[mt][1] = mfma16(a, b1, acc1[mt][1]);
    }
  }
  // v1 epilogue
  #pragma unroll
  for (int mt = 0; mt < MT3; ++mt)
    #pragma unroll
    for (int nl = 0; nl < 2; ++nl) {
      int col = wnb + (nl << 4) + l15;
      #pragma unroll
      for (int r = 0; r < 4; ++r) {
        int row = (mt << 4) + (quad << 2) + r;
        if (row < NE) {
          float v = acc1[mt][nl][r] + b2fu(s_hA[((row / Kc) << 7) + col]) +
                    b2fu(hbr[mt][nl][r]);
          s_R2[fragoff(row, col, MT3)] = f2bu(siluf(v));
        }
      }
    }
  __syncthreads();

  // ---- stage 2: m = silu(v1 @ We2) ----
  f32x4 acc2[MT3][2];
  #pragma unroll
  for (int mt = 0; mt < MT3; ++mt)
    #pragma unroll
    for (int nl = 0; nl < 2; ++nl) acc2[mt][nl] = (f32x4){0.f, 0.f, 0.f, 0.f};
  const sh8* r2v = (const sh8*)s_R2;
  for (int kt = 0; kt < 4; ++kt) {
    sh8 b0 = ((const sh8*)We2_s)[((kt << 3) + (wv << 1) + 0) * 64 + lane];
    sh8 b1 = ((const sh8*)We2_s)[((kt << 3) + (wv << 1) + 1) * 64 + lane];
    #pragma unroll
    for (int mt = 0; mt < MT3; ++mt) {
      sh8 a = r2v[(kt * MT3 + mt) * 64 + lane];
      acc2[mt][0] = mfma16(a, b0, acc2[mt][0]);
      acc2[mt][1] = mfma16(a, b1, acc2[mt][1]);
    }
  }
  __syncthreads();
  #pragma unroll
  for (int mt = 0; mt < MT3; ++mt)
    #pragma unroll
    for (int nl = 0; nl < 2; ++nl) {
      int col = wnb + (nl << 4) + l15;
      #pragma unroll
      for (int r = 0; r < 4; ++r) {
        int row = (mt << 4) + (quad << 2) + r;
        s_R2[fragoff(row, col, MT3)] = f2bu(siluf(acc2[mt][nl][r]));
      }
    }
  __syncthreads();

  // ---- aggm + stage 3: t2 = silu(m @ Wx1) ----
  for (int o = t; o < GN * HID; o += 256) {
    int g = o >> 7, col = o & 127;
    float s = 0.f;
    #pragma unroll
    for (int k = 0; k < Kc; ++k) s += b2fu(s_R2[fragoff(g * Kc + k, col, MT3)]);
    aggm[(size_t)(n0 + g) * HID + col] = __float2bfloat16(s);
  }
  f32x4 acc3[MT3][2];
  #pragma unroll
  for (int mt = 0; mt < MT3; ++mt)
    #pragma unroll
    for (int nl = 0; nl < 2; ++nl) acc3[mt][nl] = (f32x4){0.f, 0.f, 0.f, 0.f};
  for (int kt = 0; kt < 4; ++kt) {
    sh8 b0 = ((const sh8*)Wx1_s)[((kt << 3) + (wv << 1) + 0) * 64 + lane];
    sh8 b1 = ((const sh8*)Wx1_s)[((kt << 3) + (wv << 1) + 1) * 64 + lane];
    #pragma unroll
    for (int mt = 0; mt < MT3; ++mt) {
      sh8 a = r2v[(kt * MT3 + mt) * 64 + lane];
      acc3[mt][0] = mfma16(a, b0, acc3[mt][0]);
      acc3[mt][1] = mfma16(a, b1, acc3[mt][1]);
    }
  }
  __syncthreads();   // all m reads done before overwriting s_R1 (t2 target)
  #pragma unroll
  for (int mt = 0; mt < MT3; ++mt)
    #pragma unroll
    for (int nl = 0; nl < 2; ++nl) {
      int col = wnb + (nl << 4) + l15;
      #pragma unroll
      for (int r = 0; r < 4; ++r) {
        int row = (mt << 4) + (quad << 2) + r;
        s_R1[fragoff(row, col, MT3)] = f2bu(siluf(acc3[mt][nl][r]));
      }
    }
  __syncthreads();

  // ---- stage 4 (wave 0): coef = t2 @ Wx2 ----
  float* s_coef = (float*)s_R2;
  if (wv == 0) {
    f32x4 a4[MT3];
    #pragma unroll
    for (int mt = 0; mt < MT3; ++mt) a4[mt] = (f32x4){0.f, 0.f, 0.f, 0.f};
    for (int kt = 0; kt < 4; ++kt) {
      sh8 b = ((const sh8*)Wx2_s)[kt * 64 + lane];
      #pragma unroll
      for (int mt = 0; mt < MT3; ++mt) {
        sh8 a = r1v[(kt * MT3 + mt) * 64 + lane];
        a4[mt] = mfma16(a, b, a4[mt]);
      }
    }
    #pragma unroll
    for (int mt = 0; mt < MT3; ++mt)
      #pragma unroll
      for (int r = 0; r < 4; ++r) {
        int row = (mt << 4) + (quad << 2) + r;
        s_coef[(row << 4) + l15] = a4[mt][r];
      }
  }
  __syncthreads();

  // ---- stage 5: X_out = X_in + (sum_k xd*coef)*cw/K ----
  for (int o = t; o < GN * X3; o += 256) {
    int g = o / X3, rem = o - g * X3, c = rem / 3;
    float s = 0.f;
    #pragma unroll
    for (int k = 0; k < Kc; ++k) {
      int e = g * Kc + k;
      s += b2fu(s_xd[e * 44 + rem]) * s_coef[(e << 4) + c];
    }
    int gn = n0 + g;
    Xout[(size_t)gn * X3 + rem] =
        Xin[(size_t)gn * X3 + rem] + s * s_cw[g * Cc + c] * (1.0f / 9.0f);
  }
}

// ---------------------------------------------------------------------------
extern "C" void kernel_launch(void* const* d_in, const int* in_sizes, int n_in,
                              void* d_out, int out_size, void* d_ws, size_t ws_size,
                              hipStream_t stream) {
  const float* X    = (const float*)d_in[0];
  const int*   S    = (const int*)d_in[1];
  const float* Etab = (const float*)d_in[2];
  const float* Wch  = (const float*)d_in[3];
  const float* Win  = (const float*)d_in[4];
  const float* Wr   = (const float*)d_in[5];
  const float* We1  = (const float*)d_in[6];
  const float* be1  = (const float*)d_in[7];
  const float* We2  = (const float*)d_in[8];
  const float* Wx1  = (const float*)d_in[9];
  const float* Wx2  = (const float*)d_in[10];
  const float* Wh1  = (const float*)d_in[11];
  const float* Wh2  = (const float*)d_in[12];
  const float* Wf1  = (const float*)d_in[13];
  const float* Wf2  = (const float*)d_in[14];
  (void)in_sizes; (void)n_in; (void)out_size; (void)ws_size;

  char* base = (char*)d_ws;
  size_t off = 0;
  auto alloc = [&](size_t bytes) {
    void* p = base + off;
    off += (bytes + 255) & ~(size_t)255;
    return p;
  };
  int*   nbr   = (int*)  alloc((size_t)Nn * Kc * 4);
  float* Htab  = (float*)alloc(NCLS * HID * 4);
  float* cwtab = (float*)alloc(NCLS * Cc * 4);
  float* Wrpf  = (float*)alloc((size_t)NL * 256 * HID * 4);   // padded 256 rows
  float* posG  = (float*)alloc((size_t)Bc * 3 * PSTR * 4);
  float* Xa    = (float*)alloc((size_t)Nn * X3 * 4);
  float* Xb    = (float*)alloc((size_t)Nn * X3 * 4);
  float* hv    = (float*)alloc((size_t)Nn * HID * 4);
  bf16*  hAv   = (bf16*) alloc((size_t)Nn * HID * 2);
  bf16*  hBv   = (bf16*) alloc((size_t)Nn * HID * 2);
  bf16*  aggmv = (bf16*) alloc((size_t)Nn * HID * 2);
  constexpr int WRP_SZ = 8 * 8 * 512;    // KT=8 now
  constexpr int W128_SZ = 4 * 8 * 512;
  constexpr int WX2_SZ = 4 * 1 * 512;
  constexpr int WH1_SZ = 8 * 8 * 512;
  constexpr int WF2_SZ = 4 * 2 * 512;
  unsigned short* Wrp_s  = (unsigned short*)alloc((size_t)NL * WRP_SZ * 2);
  unsigned short* We2_s  = (unsigned short*)alloc((size_t)NL * W128_SZ * 2);
  unsigned short* Wx1_s  = (unsigned short*)alloc((size_t)NL * W128_SZ * 2);
  unsigned short* Wx2_s  = (unsigned short*)alloc((size_t)NL * WX2_SZ * 2);
  unsigned short* Wh1_s  = (unsigned short*)alloc((size_t)NL * WH1_SZ * 2);
  unsigned short* Wh2_s  = (unsigned short*)alloc((size_t)NL * W128_SZ * 2);
  unsigned short* We1a_s = (unsigned short*)alloc((size_t)NL * W128_SZ * 2);
  unsigned short* We1b_s = (unsigned short*)alloc((size_t)NL * W128_SZ * 2);
  unsigned short* Wf1_s  = (unsigned short*)alloc(W128_SZ * 2);
  unsigned short* Wf2_s  = (unsigned short*)alloc(WF2_SZ * 2);

  wrp_kernel<<<NL * 256, 128, 0, stream>>>(Wr, We1, Wrpf);
  htab_kernel<<<NCLS, 128, 0, stream>>>(Etab, Win, Wch, Htab, cwtab);
  posx_kernel<<<79, 256, 0, stream>>>(X, posG);
  knn_kernel<<<Bc * ((Lc + KR2 - 1) / KR2), 256, 0, stream>>>(posG, nbr);

  ShufArgs sa;
  for (int l = 0; l < NL; ++l) {
    int e = l * 8;
    sa.src[e+0] = Wrpf + (size_t)l * 256 * HID;      sa.dst[e+0] = Wrp_s  + (size_t)l * WRP_SZ;
    sa.K[e+0] = 256; sa.N[e+0] = HID; sa.KT[e+0] = 8; sa.NT[e+0] = 8;
    sa.src[e+1] = We2 + (size_t)l * HID * HID;       sa.dst[e+1] = We2_s  + (size_t)l * W128_SZ;
    sa.K[e+1] = HID; sa.N[e+1] = HID; sa.KT[e+1] = 4; sa.NT[e+1] = 8;
    sa.src[e+2] = Wx1 + (size_t)l * HID * HID;       sa.dst[e+2] = Wx1_s  + (size_t)l * W128_SZ;
    sa.K[e+2] = HID; sa.N[e+2] = HID; sa.KT[e+2] = 4; sa.NT[e+2] = 8;
    sa.src[e+3] = Wx2 + (size_t)l * HID * Cc;        sa.dst[e+3] = Wx2_s  + (size_t)l * WX2_SZ;
    sa.K[e+3] = HID; sa.N[e+3] = Cc;  sa.KT[e+3] = 4; sa.NT[e+3] = 1;
    sa.src[e+4] = Wh1 + (size_t)l * 256 * HID;       sa.dst[e+4] = Wh1_s  + (size_t)l * WH1_SZ;
    sa.K[e+4] = 256; sa.N[e+4] = HID; sa.KT[e+4] = 8; sa.NT[e+4] = 8;
    sa.src[e+5] = Wh2 + (size_t)l * HID * HID;       sa.dst[e+5] = Wh2_s  + (size_t)l * W128_SZ;
    sa.K[e+5] = HID; sa.N[e+5] = HID; sa.KT[e+5] = 4; sa.NT[e+5] = 8;
    sa.src[e+6] = We1 + (size_t)l * 384 * HID;       sa.dst[e+6] = We1a_s + (size_t)l * W128_SZ;
    sa.K[e+6] = HID; sa.N[e+6] = HID; sa.KT[e+6] = 4; sa.NT[e+6] = 8;
    sa.src[e+7] = We1 + (size_t)l * 384 * HID + (size_t)HID * HID;
    sa.dst[e+7] = We1b_s + (size_t)l * W128_SZ;
    sa.K[e+7] = HID; sa.N[e+7] = HID; sa.KT[e+7] = 4; sa.NT[e+7] = 8;
  }
  sa.src[24] = Wf1; sa.dst[24] = Wf1_s; sa.K[24] = HID; sa.N[24] = HID;
  sa.KT[24] = 4; sa.NT[24] = 8;
  sa.src[25] = Wf2; sa.dst[25] = Wf2_s; sa.K[25] = HID; sa.N[25] = NCLS;
  sa.KT[25] = 4; sa.NT[25] = 2;
  shufb_kernel<<<dim3(16, NSH), 256, 0, stream>>>(sa);

  nodeABm_kernel<<<Nn / 16, 256, 0, stream>>>(S, Htab, hv, We1a_s, We1b_s, be1,
                                              hAv, hBv);

  float* out = (float*)d_out;
  float* outX = out + (size_t)Nn * NCLS;
  const float* Xi = X;
  for (int l = 0; l < NL; ++l) {
    float* Xo = (l == NL - 1) ? outX : ((l == 0) ? Xb : Xa);
    edge_kernel<<<Nn / GN, 256, 0, stream>>>(
        Xi, Xo, hAv, hBv, S, cwtab, nbr,
        Wrp_s + (size_t)l * WRP_SZ, We2_s + (size_t)l * W128_SZ,
        Wx1_s + (size_t)l * W128_SZ, Wx2_s + (size_t)l * WX2_SZ, aggmv);
    if (l < NL - 1) {
      fupdAB_kernel<<<Nn / 16, 256, 0, stream>>>(
          hv, aggmv, Wh1_s + (size_t)l * WH1_SZ, Wh2_s + (size_t)l * W128_SZ,
          We1a_s + (size_t)(l + 1) * W128_SZ, We1b_s + (size_t)(l + 1) * W128_SZ,
          be1 + (l + 1) * HID, hAv, hBv);
    } else {
      fupdF_kernel<<<Nn / 16, 256, 0, stream>>>(
          hv, aggmv, Wh1_s + (size_t)l * WH1_SZ, Wh2_s + (size_t)l * W128_SZ,
          Wf1_s, Wf2_s, out);
    }
    Xi = Xo;
  }
}

// Round 16
// 499.323 us; speedup vs baseline: 1.1155x; 1.1155x over previous
//
#include <hip/hip_runtime.h>
#include <hip/hip_bf16.h>

typedef __hip_bfloat16 bf16;

// Problem constants
constexpr int Bc  = 8;
constexpr int Lc  = 2500;
constexpr int Cc  = 14;
constexpr int Kc  = 9;
constexpr int Nn  = Bc * Lc;     // 20000
constexpr int NCLS = 20;
constexpr int HID = 128;
constexpr int NL  = 3;
constexpr int CC  = Cc * Cc;     // 196
constexpr int X3  = Cc * 3;      // 42

typedef __bf16 bf16x8 __attribute__((ext_vector_type(8)));
typedef short  sh8    __attribute__((ext_vector_type(8)));
typedef float  f32x4  __attribute__((ext_vector_type(4)));

__device__ __forceinline__ float b2f(bf16 x) { return __bfloat162float(x); }
__device__ __forceinline__ float b2fu(unsigned short u) {
  return __uint_as_float(((unsigned int)u) << 16);
}
__device__ __forceinline__ unsigned short f2bu(float x) {
  bf16 h = __float2bfloat16(x);
  return *reinterpret_cast<unsigned short*>(&h);
}
// fast silu: v_exp-based expf + v_rcp (no full-precision divide)
__device__ __forceinline__ float siluf(float x) {
  return x * __builtin_amdgcn_rcpf(1.0f + __expf(-x));
}
__device__ __forceinline__ int clampi(int v, int n) {
  return ((unsigned)v < (unsigned)n) ? v : 0;
}
__device__ __forceinline__ void unpk2(unsigned int u, float& a, float& b) {
  a = __uint_as_float(u << 16);
  b = __uint_as_float(u & 0xffff0000u);
}

__device__ __forceinline__ f32x4 mfma16(sh8 a, sh8 b, f32x4 c) {
  return __builtin_amdgcn_mfma_f32_16x16x32_bf16(
      __builtin_bit_cast(bf16x8, a), __builtin_bit_cast(bf16x8, b), c, 0, 0, 0);
}

// A/activation fragment-linear offset (in shorts). MT m-tiles; tile = 512 shorts.
__device__ __forceinline__ int fragoff(int e, int k, int MT) {
  return (((k >> 5) * MT + (e >> 4)) << 9) +
         (((e & 15) + (((k >> 3) & 3) << 4)) << 3) + (k & 7);
}

// ---------------------------------------------------------------------------
// Wrp[l] = Wr[l] @ We1[l][256:384,:]  (fp32, fold radial proj into edge MLP)
// ---------------------------------------------------------------------------
__global__ __launch_bounds__(128) void wrp_kernel(const float* __restrict__ Wr,
                                                  const float* __restrict__ We1,
                                                  float* __restrict__ Wrp) {
  int l = blockIdx.x / CC, j = blockIdx.x % CC;
  int t = threadIdx.x;
  __shared__ float row[HID];
  row[t] = Wr[(size_t)(l * CC + j) * HID + t];
  __syncthreads();
  float acc = 0.f;
  #pragma unroll 4
  for (int k = 0; k < HID; ++k)
    acc += row[k] * We1[(size_t)(l * 384 + 256 + k) * HID + t];
  Wrp[(size_t)(l * CC + j) * HID + t] = acc;
}

// ---------------------------------------------------------------------------
// Batched weight shuffle: fp32 KxN -> B-fragment-linear bf16 (zero-padded).
// ---------------------------------------------------------------------------
constexpr int NSH = 26;
struct ShufArgs {
  const float* src[NSH];
  unsigned short* dst[NSH];
  int K[NSH], N[NSH], KT[NSH], NT[NSH];
};

__global__ void shufb_kernel(ShufArgs a) {
  int e = blockIdx.y;
  int K = a.K[e], N = a.N[e], NT = a.NT[e];
  int total = a.KT[e] * NT * 512;
  const float* W = a.src[e];
  unsigned short* out = a.dst[e];
  for (int idx = blockIdx.x * blockDim.x + threadIdx.x; idx < total;
       idx += gridDim.x * blockDim.x) {
    int j = idx & 7;
    int lane = (idx >> 3) & 63;
    int nt = (idx >> 9) % NT;
    int kt = idx / (512 * NT);
    int k = kt * 32 + ((lane >> 4) << 3) + j;
    int n = nt * 16 + (lane & 15);
    float v = (k < K && n < N) ? W[(size_t)k * N + n] : 0.f;
    out[idx] = f2bu(v);
  }
}

// Htab = E_tab @ Win (20x128); cwtab = row-softmax(Wchan) (20x14)
__global__ __launch_bounds__(128) void htab_kernel(const float* __restrict__ Et,
                                                   const float* __restrict__ Win,
                                                   const float* __restrict__ Wch,
                                                   float* __restrict__ Htab,
                                                   float* __restrict__ cwtab) {
  int r = blockIdx.x, t = threadIdx.x;
  __shared__ float e[HID];
  e[t] = Et[r * HID + t];
  __syncthreads();
  float acc = 0.f;
  #pragma unroll 4
  for (int k = 0; k < HID; ++k) acc += e[k] * Win[k * HID + t];
  Htab[r * HID + t] = acc;
  if (t == 0) {
    float v[Cc];
    float mx = -1e30f;
    for (int c = 0; c < Cc; ++c) { v[c] = Wch[r * Cc + c]; mx = fmaxf(mx, v[c]); }
    float s = 0.f;
    for (int c = 0; c < Cc; ++c) { v[c] = __expf(v[c] - mx); s += v[c]; }
    float inv = 1.0f / s;
    for (int c = 0; c < Cc; ++c) cwtab[r * Cc + c] = v[c] * inv;
  }
}

// ---------------------------------------------------------------------------
// Extract CA coords to compact global SoA: posG[comp][axis][PSTR]
// ---------------------------------------------------------------------------
constexpr int PSTR = 2512;

__global__ void posx_kernel(const float* __restrict__ X, float* __restrict__ posG) {
  int total = Bc * PSTR;
  for (int i = blockIdx.x * blockDim.x + threadIdx.x; i < total;
       i += gridDim.x * blockDim.x) {
    int comp = i / PSTR, j = i - comp * PSTR;
    float x = 1e30f, y = 1e30f, z = 1e30f;
    if (j < Lc) {
      size_t g = (size_t)(comp * Lc + j) * X3;
      x = X[g + 3]; y = X[g + 4]; z = X[g + 5];
    }
    float* b = posG + (size_t)comp * 3 * PSTR;
    b[j] = x; b[PSTR + j] = y; b[2 * PSTR + j] = z;
  }
}

// ---------------------------------------------------------------------------
// kNN, zero-LDS: 8 rows/block, 32 threads/row, 80 candidates/thread.
// 64-bit shfl_xor min-reduction (masks<=16 stay in-row) merges the 32 sorted
// top-9 lists; key (d2_bits<<32)|idx gives exact jax top_k stable order.
// ---------------------------------------------------------------------------
constexpr int KR2 = 8;
constexpr int KC2 = 80;

__global__ __launch_bounds__(256) void knn_kernel(const float* __restrict__ posG,
                                                  int* __restrict__ nbr) {
  constexpr int bpc = (Lc + KR2 - 1) / KR2;   // 313
  int comp = blockIdx.x / bpc, rb = blockIdx.x % bpc;
  int t = threadIdx.x;
  int rl = t >> 5, q = t & 31;
  int r = rb * KR2 + rl;
  const float* px = posG + (size_t)comp * 3 * PSTR;
  const float* py = px + PSTR;
  const float* pz = py + PSTR;

  float bd[Kc];
  int   bi[Kc];
  #pragma unroll
  for (int k = 0; k < Kc; ++k) { bd[k] = __int_as_float(0x7f800000); bi[k] = 0x7fffffff; }

  if (r < Lc) {
    float rx = px[r], ry = py[r], rz = pz[r];
    int c0 = q * KC2;
    int c1 = c0 + KC2; if (c1 > Lc) c1 = Lc;
    for (int i = c0; i < c1; i += 4) {
      float4 xs = *(const float4*)(px + i);
      float4 ys = *(const float4*)(py + i);
      float4 zs = *(const float4*)(pz + i);
      float d2v[4];
      {
        float dx, dy, dz;
        dx = rx - xs.x; dy = ry - ys.x; dz = rz - zs.x; d2v[0] = dx*dx + dy*dy + dz*dz;
        dx = rx - xs.y; dy = ry - ys.y; dz = rz - zs.y; d2v[1] = dx*dx + dy*dy + dz*dz;
        dx = rx - xs.z; dy = ry - ys.z; dz = rz - zs.z; d2v[2] = dx*dx + dy*dy + dz*dz;
        dx = rx - xs.w; dy = ry - ys.w; dz = rz - zs.w; d2v[3] = dx*dx + dy*dy + dz*dz;
      }
      #pragma unroll
      for (int u = 0; u < 4; ++u) {
        int ii = i + u;
        float d2 = d2v[u];
        if (ii != r && d2 < bd[Kc - 1]) {
          bd[Kc - 1] = d2; bi[Kc - 1] = ii;
          #pragma unroll
          for (int p = Kc - 1; p > 0; --p) {
            if (bd[p] < bd[p - 1]) {
              float td = bd[p]; bd[p] = bd[p - 1]; bd[p - 1] = td;
              int   ti = bi[p]; bi[p] = bi[p - 1]; bi[p - 1] = ti;
            }
          }
        }
      }
    }
  }

  int gbase = (comp * Lc + r) * Kc;
  #pragma unroll
  for (int k = 0; k < Kc; ++k) {
    unsigned long long mykey =
        ((unsigned long long)__float_as_uint(bd[0]) << 32) | (unsigned int)bi[0];
    unsigned long long w = mykey;
    #pragma unroll
    for (int m = 1; m <= 16; m <<= 1) {
      unsigned long long o = __shfl_xor(w, m);
      if (o < w) w = o;
    }
    if (r < Lc && q == k)
      nbr[gbase + k] = comp * Lc + (int)(unsigned int)(w & 0xffffffffULL);
    if (mykey == w) {
      #pragma unroll
      for (int s = 0; s < Kc - 1; ++s) { bd[s] = bd[s + 1]; bi[s] = bi[s + 1]; }
      bd[Kc - 1] = __int_as_float(0x7f800000); bi[Kc - 1] = 0x7fffffff;
    }
  }
}

// ---------------------------------------------------------------------------
// MFMA node AB (layer 0), with fused embedding gather:
//   h[n] = Htab[S[n]]  (written to hv);  hA = h@We1a + be1, hB = h@We1b
// ---------------------------------------------------------------------------
__global__ __launch_bounds__(256) void nodeABm_kernel(
    const int* __restrict__ S, const float* __restrict__ Htab,
    float* __restrict__ hv,
    const unsigned short* __restrict__ We1a_s, const unsigned short* __restrict__ We1b_s,
    const float* __restrict__ be1n, bf16* __restrict__ hA, bf16* __restrict__ hB) {
  __shared__ __align__(16) unsigned short sB[4 * 512];
  int t = threadIdx.x, n0 = blockIdx.x * 16;
  int lane = t & 63, wv = t >> 6, quad = lane >> 4, l15 = lane & 15, wnb = wv << 5;

  for (int o = t; o < 16 * HID; o += 256) {
    int row = o >> 7, k = o & 127;
    float v = Htab[clampi(S[n0 + row], NCLS) * HID + k];
    hv[(size_t)(n0 + row) * HID + k] = v;
    sB[fragoff(row, k, 1)] = f2bu(v);
  }
  __syncthreads();

  f32x4 a3[2] = {{0,0,0,0},{0,0,0,0}}, a4[2] = {{0,0,0,0},{0,0,0,0}};
  const sh8* sBv = (const sh8*)sB;
  for (int kt = 0; kt < 4; ++kt) {
    sh8 a = sBv[kt * 64 + lane];
    sh8 b0 = ((const sh8*)We1a_s)[((kt << 3) + (wv << 1) + 0) * 64 + lane];
    sh8 b1 = ((const sh8*)We1a_s)[((kt << 3) + (wv << 1) + 1) * 64 + lane];
    sh8 c0 = ((const sh8*)We1b_s)[((kt << 3) + (wv << 1) + 0) * 64 + lane];
    sh8 c1 = ((const sh8*)We1b_s)[((kt << 3) + (wv << 1) + 1) * 64 + lane];
    a3[0] = mfma16(a, b0, a3[0]); a3[1] = mfma16(a, b1, a3[1]);
    a4[0] = mfma16(a, c0, a4[0]); a4[1] = mfma16(a, c1, a4[1]);
  }
  #pragma unroll
  for (int nl = 0; nl < 2; ++nl) {
    int col = wnb + (nl << 4) + l15;
    float be = be1n[col];
    #pragma unroll
    for (int r = 0; r < 4; ++r) {
      int row = (quad << 2) + r;
      hA[(size_t)(n0 + row) * HID + col] = __float2bfloat16(a3[nl][r] + be);
      hB[(size_t)(n0 + row) * HID + col] = __float2bfloat16(a4[nl][r]);
    }
  }
}

// ---------------------------------------------------------------------------
// MFMA fused node update + next AB
// ---------------------------------------------------------------------------
__global__ __launch_bounds__(256) void fupdAB_kernel(
    float* __restrict__ h, const bf16* __restrict__ aggm,
    const unsigned short* __restrict__ Wh1_s, const unsigned short* __restrict__ Wh2_s,
    const unsigned short* __restrict__ We1a_s, const unsigned short* __restrict__ We1b_s,
    const float* __restrict__ be1n, bf16* __restrict__ hA, bf16* __restrict__ hB) {
  __shared__ __align__(16) unsigned short sA[8 * 512];
  __shared__ __align__(16) unsigned short sB[4 * 512];
  int t = threadIdx.x, n0 = blockIdx.x * 16;
  int lane = t & 63, wv = t >> 6, quad = lane >> 4, l15 = lane & 15, wnb = wv << 5;

  for (int o = t; o < 16 * 256; o += 256) {
    int row = o >> 8, k = o & 255;
    float v = (k < HID) ? h[(size_t)(n0 + row) * HID + k]
                        : b2f(aggm[(size_t)(n0 + row) * HID + (k - HID)]);
    sA[fragoff(row, k, 1)] = f2bu(v);
  }
  __syncthreads();

  f32x4 a1[2] = {{0,0,0,0},{0,0,0,0}};
  const sh8* sAv = (const sh8*)sA;
  for (int kt = 0; kt < 8; ++kt) {
    sh8 a = sAv[kt * 64 + lane];
    sh8 b0 = ((const sh8*)Wh1_s)[((kt << 3) + (wv << 1) + 0) * 64 + lane];
    sh8 b1 = ((const sh8*)Wh1_s)[((kt << 3) + (wv << 1) + 1) * 64 + lane];
    a1[0] = mfma16(a, b0, a1[0]);
    a1[1] = mfma16(a, b1, a1[1]);
  }
  #pragma unroll
  for (int nl = 0; nl < 2; ++nl) {
    int col = wnb + (nl << 4) + l15;
    #pragma unroll
    for (int r = 0; r < 4; ++r)
      sB[fragoff((quad << 2) + r, col, 1)] = f2bu(siluf(a1[nl][r]));
  }
  __syncthreads();

  f32x4 a2[2] = {{0,0,0,0},{0,0,0,0}};
  const sh8* sBv = (const sh8*)sB;
  for (int kt = 0; kt < 4; ++kt) {
    sh8 a = sBv[kt * 64 + lane];
    sh8 b0 = ((const sh8*)Wh2_s)[((kt << 3) + (wv << 1) + 0) * 64 + lane];
    sh8 b1 = ((const sh8*)Wh2_s)[((kt << 3) + (wv << 1) + 1) * 64 + lane];
    a2[0] = mfma16(a, b0, a2[0]);
    a2[1] = mfma16(a, b1, a2[1]);
  }
  float hn[2][4];
  #pragma unroll
  for (int nl = 0; nl < 2; ++nl) {
    int col = wnb + (nl << 4) + l15;
    #pragma unroll
    for (int r = 0; r < 4; ++r) {
      int row = (quad << 2) + r;
      float v = h[(size_t)(n0 + row) * HID + col] + a2[nl][r];
      h[(size_t)(n0 + row) * HID + col] = v;
      hn[nl][r] = v;
    }
  }
  __syncthreads();
  #pragma unroll
  for (int nl = 0; nl < 2; ++nl) {
    int col = wnb + (nl << 4) + l15;
    #pragma unroll
    for (int r = 0; r < 4; ++r)
      sB[fragoff((quad << 2) + r, col, 1)] = f2bu(hn[nl][r]);
  }
  __syncthreads();

  f32x4 a3[2] = {{0,0,0,0},{0,0,0,0}}, a4[2] = {{0,0,0,0},{0,0,0,0}};
  for (int kt = 0; kt < 4; ++kt) {
    sh8 a = sBv[kt * 64 + lane];
    sh8 b0 = ((const sh8*)We1a_s)[((kt << 3) + (wv << 1) + 0) * 64 + lane];
    sh8 b1 = ((const sh8*)We1a_s)[((kt << 3) + (wv << 1) + 1) * 64 + lane];
    sh8 c0 = ((const sh8*)We1b_s)[((kt << 3) + (wv << 1) + 0) * 64 + lane];
    sh8 c1 = ((const sh8*)We1b_s)[((kt << 3) + (wv << 1) + 1) * 64 + lane];
    a3[0] = mfma16(a, b0, a3[0]); a3[1] = mfma16(a, b1, a3[1]);
    a4[0] = mfma16(a, c0, a4[0]); a4[1] = mfma16(a, c1, a4[1]);
  }
  #pragma unroll
  for (int nl = 0; nl < 2; ++nl) {
    int col = wnb + (nl << 4) + l15;
    float be = be1n[col];
    #pragma unroll
    for (int r = 0; r < 4; ++r) {
      int row = (quad << 2) + r;
      hA[(size_t)(n0 + row) * HID + col] = __float2bfloat16(a3[nl][r] + be);
      hB[(size_t)(n0 + row) * HID + col] = __float2bfloat16(a4[nl][r]);
    }
  }
}

// ---------------------------------------------------------------------------
// MFMA fused last node update + final FFN
// ---------------------------------------------------------------------------
__global__ __launch_bounds__(256) void fupdF_kernel(
    const float* __restrict__ h, const bf16* __restrict__ aggm,
    const unsigned short* __restrict__ Wh1_s, const unsigned short* __restrict__ Wh2_s,
    const unsigned short* __restrict__ Wf1_s, const unsigned short* __restrict__ Wf2_s,
    float* __restrict__ out) {
  __shared__ __align__(16) unsigned short sA[8 * 512];
  __shared__ __align__(16) unsigned short sB[4 * 512];
  int t = threadIdx.x, n0 = blockIdx.x * 16;
  int lane = t & 63, wv = t >> 6, quad = lane >> 4, l15 = lane & 15, wnb = wv << 5;

  for (int o = t; o < 16 * 256; o += 256) {
    int row = o >> 8, k = o & 255;
    float v = (k < HID) ? h[(size_t)(n0 + row) * HID + k]
                        : b2f(aggm[(size_t)(n0 + row) * HID + (k - HID)]);
    sA[fragoff(row, k, 1)] = f2bu(v);
  }
  __syncthreads();

  f32x4 a1[2] = {{0,0,0,0},{0,0,0,0}};
  const sh8* sAv = (const sh8*)sA;
  for (int kt = 0; kt < 8; ++kt) {
    sh8 a = sAv[kt * 64 + lane];
    sh8 b0 = ((const sh8*)Wh1_s)[((kt << 3) + (wv << 1) + 0) * 64 + lane];
    sh8 b1 = ((const sh8*)Wh1_s)[((kt << 3) + (wv << 1) + 1) * 64 + lane];
    a1[0] = mfma16(a, b0, a1[0]);
    a1[1] = mfma16(a, b1, a1[1]);
  }
  #pragma unroll
  for (int nl = 0; nl < 2; ++nl) {
    int col = wnb + (nl << 4) + l15;
    #pragma unroll
    for (int r = 0; r < 4; ++r)
      sB[fragoff((quad << 2) + r, col, 1)] = f2bu(siluf(a1[nl][r]));
  }
  __syncthreads();

  f32x4 a2[2] = {{0,0,0,0},{0,0,0,0}};
  const sh8* sBv = (const sh8*)sB;
  for (int kt = 0; kt < 4; ++kt) {
    sh8 a = sBv[kt * 64 + lane];
    sh8 b0 = ((const sh8*)Wh2_s)[((kt << 3) + (wv << 1) + 0) * 64 + lane];
    sh8 b1 = ((const sh8*)Wh2_s)[((kt << 3) + (wv << 1) + 1) * 64 + lane];
    a2[0] = mfma16(a, b0, a2[0]);
    a2[1] = mfma16(a, b1, a2[1]);
  }
  float u2[2][4];
  #pragma unroll
  for (int nl = 0; nl < 2; ++nl) {
    int col = wnb + (nl << 4) + l15;
    #pragma unroll
    for (int r = 0; r < 4; ++r) {
      int row = (quad << 2) + r;
      u2[nl][r] = siluf(h[(size_t)(n0 + row) * HID + col] + a2[nl][r]);
    }
  }
  __syncthreads();
  #pragma unroll
  for (int nl = 0; nl < 2; ++nl) {
    int col = wnb + (nl << 4) + l15;
    #pragma unroll
    for (int r = 0; r < 4; ++r)
      sB[fragoff((quad << 2) + r, col, 1)] = f2bu(u2[nl][r]);
  }
  __syncthreads();

  f32x4 a3[2] = {{0,0,0,0},{0,0,0,0}};
  for (int kt = 0; kt < 4; ++kt) {
    sh8 a = sBv[kt * 64 + lane];
    sh8 b0 = ((const sh8*)Wf1_s)[((kt << 3) + (wv << 1) + 0) * 64 + lane];
    sh8 b1 = ((const sh8*)Wf1_s)[((kt << 3) + (wv << 1) + 1) * 64 + lane];
    a3[0] = mfma16(a, b0, a3[0]);
    a3[1] = mfma16(a, b1, a3[1]);
  }
  #pragma unroll
  for (int nl = 0; nl < 2; ++nl) {
    int col = wnb + (nl << 4) + l15;
    #pragma unroll
    for (int r = 0; r < 4; ++r)
      sA[fragoff((quad << 2) + r, col, 1)] = f2bu(siluf(a3[nl][r]));
  }
  __syncthreads();

  if (wv < 2) {
    f32x4 a5 = {0.f, 0.f, 0.f, 0.f};
    for (int kt = 0; kt < 4; ++kt) {
      sh8 a = sAv[kt * 64 + lane];
      sh8 b = ((const sh8*)Wf2_s)[(kt * 2 + wv) * 64 + lane];
      a5 = mfma16(a, b, a5);
    }
    int col = (wv << 4) + l15;
    if (col < NCLS) {
      #pragma unroll
      for (int r = 0; r < 4; ++r) {
        int row = (quad << 2) + r;
        out[(size_t)(n0 + row) * NCLS + col] = a5[r];
      }
    }
  }
}

// ---------------------------------------------------------------------------
// MFMA edge kernel — single-pass stage 1 (K=224), hB direct-from-global
// prefetch, 38.4 KB LDS -> 4 blocks/CU.  (Round-14 proven structure.)
// ---------------------------------------------------------------------------
constexpr int GN  = 4;
constexpr int NE  = GN * Kc;     // 36
constexpr int MT3 = 3;           // m-tiles (M padded to 48)

__global__ __launch_bounds__(256) void edge_kernel(
    const float* __restrict__ Xin, float* __restrict__ Xout,
    const bf16* __restrict__ hA, const bf16* __restrict__ hB,
    const int* __restrict__ S, const float* __restrict__ cwtab,
    const int* __restrict__ nbr,
    const unsigned short* __restrict__ Wrp_s, const unsigned short* __restrict__ We2_s,
    const unsigned short* __restrict__ Wx1_s, const unsigned short* __restrict__ Wx2_s,
    bf16* __restrict__ aggm) {
  __shared__ __align__(16) unsigned short s_R1[48 * 224];  // 21504 B
  __shared__ __align__(16) unsigned short s_R2[48 * 128];  // 12288 B
  __shared__ __align__(16) unsigned short s_xd[NE * 44];   //  3168 B
  __shared__ __align__(16) unsigned short s_hA[GN * 128];  //  1024 B
  __shared__ float s_cw[GN * Cc];
  __shared__ int   s_dst[NE];

  int t = threadIdx.x;
  int n0 = blockIdx.x * GN;
  int lane = t & 63, wv = t >> 6;
  int quad = lane >> 4, l15 = lane & 15;
  int wnb = wv << 5;

  if (t < NE) s_dst[t] = clampi(nbr[n0 * Kc + t], Nn);
  if (t >= 64 && t < 64 + GN * Cc) {
    int o = t - 64;
    s_cw[o] = cwtab[clampi(S[n0 + o / Cc], NCLS) * Cc + o % Cc];
  }
  {
    uint4* r1 = (uint4*)s_R1;
    for (int o = t; o < 1344; o += 256) r1[o] = make_uint4(0u, 0u, 0u, 0u);
    uint4* r2 = (uint4*)s_R2;
    for (int o = t; o < 768; o += 256) r2[o] = make_uint4(0u, 0u, 0u, 0u);
    const unsigned int* src = (const unsigned int*)(hA + (size_t)n0 * HID);
    unsigned int* dA = (unsigned int*)s_hA;
    for (int o = t; o < GN * 64; o += 256) dA[o] = src[o];
  }
  __syncthreads();

  // prefetch hB fragments direct from global (latency hidden by stage-1 MFMA)
  unsigned short hbr[MT3][2][4];
  {
    const unsigned short* hbu = (const unsigned short*)hB;
    #pragma unroll
    for (int mt = 0; mt < MT3; ++mt)
      #pragma unroll
      for (int nl = 0; nl < 2; ++nl) {
        int col = wnb + (nl << 4) + l15;
        #pragma unroll
        for (int r = 0; r < 4; ++r) {
          int row = (mt << 4) + (quad << 2) + r;
          hbr[mt][nl][r] =
              (row < NE) ? hbu[(size_t)s_dst[row] * HID + col] : (unsigned short)0;
        }
      }
  }

  for (int o = t; o < NE * X3; o += 256) {
    int e = o / X3, i = o - e * X3;
    float v = Xin[(size_t)(n0 + e / Kc) * X3 + i] - Xin[(size_t)s_dst[e] * X3 + i];
    s_xd[e * 44 + i] = f2bu(v);
  }
  __syncthreads();

  // ---- rad -> R1 frag-linear: thread = (e, jc); 28 j's per thread, no div ----
  if (t < 252) {
    int e = t / 7, jc = t - (t / 7) * 7;
    const unsigned int* xu = (const unsigned int*)(s_xd + e * 44);
    unsigned int u[21];
    #pragma unroll
    for (int i = 0; i < 21; ++i) u[i] = xu[i];
    float xdv[42];
    #pragma unroll
    for (int i = 0; i < 21; ++i) unpk2(u[i], xdv[2 * i], xdv[2 * i + 1]);
    #pragma unroll
    for (int half = 0; half < 2; ++half) {
      int c = 2 * jc + half;
      const unsigned short* xe = s_xd + e * 44;
      float xc0 = b2fu(xe[c * 3 + 0]);
      float xc1 = b2fu(xe[c * 3 + 1]);
      float xc2 = b2fu(xe[c * 3 + 2]);
      int jbase = c * Cc;
      #pragma unroll
      for (int d = 0; d < 14; ++d) {
        float v = (xc0 * xdv[d * 3 + 0] + xc1 * xdv[d * 3 + 1] +
                   xc2 * xdv[d * 3 + 2]) * (1.0f / 14.0f);
        s_R1[fragoff(e, jbase + d, MT3)] = f2bu(v);
      }
    }
  }
  __syncthreads();

  f32x4 acc1[MT3][2];
  #pragma unroll
  for (int mt = 0; mt < MT3; ++mt)
    #pragma unroll
    for (int nl = 0; nl < 2; ++nl) acc1[mt][nl] = (f32x4){0.f, 0.f, 0.f, 0.f};
  const sh8* r1v = (const sh8*)s_R1;
  for (int kt = 0; kt < 7; ++kt) {
    sh8 b0 = ((const sh8*)Wrp_s)[((kt << 3) + (wv << 1) + 0) * 64 + lane];
    sh8 b1 = ((const sh8*)Wrp_s)[((kt << 3) + (wv << 1) + 1) * 64 + lane];
    #pragma unroll
    for (int mt = 0; mt < MT3; ++mt) {
      sh8 a = r1v[(kt * MT3 + mt) * 64 + lane];
      acc1[mt][0] = mfma16(a, b0, acc1[mt][0]);
      acc1[mt][1] = mfma16(a, b1, acc1[mt][1]);
    }
  }
  #pragma unroll
  for (int mt = 0; mt < MT3; ++mt)
    #pragma unroll
    for (int nl = 0; nl < 2; ++nl) {
      int col = wnb + (nl << 4) + l15;
      #pragma unroll
      for (int r = 0; r < 4; ++r) {
        int row = (mt << 4) + (quad << 2) + r;
        if (row < NE) {
          float v = acc1[mt][nl][r] + b2fu(s_hA[((row / Kc) << 7) + col]) +
                    b2fu(hbr[mt][nl][r]);
          s_R2[fragoff(row, col, MT3)] = f2bu(siluf(v));
        }
      }
    }
  __syncthreads();

  f32x4 acc2[MT3][2];
  #pragma unroll
  for (int mt = 0; mt < MT3; ++mt)
    #pragma unroll
    for (int nl = 0; nl < 2; ++nl) acc2[mt][nl] = (f32x4){0.f, 0.f, 0.f, 0.f};
  const sh8* r2v = (const sh8*)s_R2;
  for (int kt = 0; kt < 4; ++kt) {
    sh8 b0 = ((const sh8*)We2_s)[((kt << 3) + (wv << 1) + 0) * 64 + lane];
    sh8 b1 = ((const sh8*)We2_s)[((kt << 3) + (wv << 1) + 1) * 64 + lane];
    #pragma unroll
    for (int mt = 0; mt < MT3; ++mt) {
      sh8 a = r2v[(kt * MT3 + mt) * 64 + lane];
      acc2[mt][0] = mfma16(a, b0, acc2[mt][0]);
      acc2[mt][1] = mfma16(a, b1, acc2[mt][1]);
    }
  }
  __syncthreads();
  #pragma unroll
  for (int mt = 0; mt < MT3; ++mt)
    #pragma unroll
    for (int nl = 0; nl < 2; ++nl) {
      int col = wnb + (nl << 4) + l15;
      #pragma unroll
      for (int r = 0; r < 4; ++r) {
        int row = (mt << 4) + (quad << 2) + r;
        s_R2[fragoff(row, col, MT3)] = f2bu(siluf(acc2[mt][nl][r]));
      }
    }
  __syncthreads();

  for (int o = t; o < GN * HID; o += 256) {
    int g = o >> 7, col = o & 127;
    float s = 0.f;
    #pragma unroll
    for (int k = 0; k < Kc; ++k) s += b2fu(s_R2[fragoff(g * Kc + k, col, MT3)]);
    aggm[(size_t)(n0 + g) * HID + col] = __float2bfloat16(s);
  }
  f32x4 acc3[MT3][2];
  #pragma unroll
  for (int mt = 0; mt < MT3; ++mt)
    #pragma unroll
    for (int nl = 0; nl < 2; ++nl) acc3[mt][nl] = (f32x4){0.f, 0.f, 0.f, 0.f};
  for (int kt = 0; kt < 4; ++kt) {
    sh8 b0 = ((const sh8*)Wx1_s)[((kt << 3) + (wv << 1) + 0) * 64 + lane];
    sh8 b1 = ((const sh8*)Wx1_s)[((kt << 3) + (wv << 1) + 1) * 64 + lane];
    #pragma unroll
    for (int mt = 0; mt < MT3; ++mt) {
      sh8 a = r2v[(kt * MT3 + mt) * 64 + lane];
      acc3[mt][0] = mfma16(a, b0, acc3[mt][0]);
      acc3[mt][1] = mfma16(a, b1, acc3[mt][1]);
    }
  }
  #pragma unroll
  for (int mt = 0; mt < MT3; ++mt)
    #pragma unroll
    for (int nl = 0; nl < 2; ++nl) {
      int col = wnb + (nl << 4) + l15;
      #pragma unroll
      for (int r = 0; r < 4; ++r) {
        int row = (mt << 4) + (quad << 2) + r;
        s_R1[fragoff(row, col, MT3)] = f2bu(siluf(acc3[mt][nl][r]));
      }
    }
  __syncthreads();

  float* s_coef = (float*)s_R2;
  if (wv == 0) {
    f32x4 a4[MT3];
    #pragma unroll
    for (int mt = 0; mt < MT3; ++mt) a4[mt] = (f32x4){0.f, 0.f, 0.f, 0.f};
    for (int kt = 0; kt < 4; ++kt) {
      sh8 b = ((const sh8*)Wx2_s)[kt * 64 + lane];
      #pragma unroll
      for (int mt = 0; mt < MT3; ++mt) {
        sh8 a = r1v[(kt * MT3 + mt) * 64 + lane];
        a4[mt] = mfma16(a, b, a4[mt]);
      }
    }
    #pragma unroll
    for (int mt = 0; mt < MT3; ++mt)
      #pragma unroll
      for (int r = 0; r < 4; ++r) {
        int row = (mt << 4) + (quad << 2) + r;
        s_coef[(row << 4) + l15] = a4[mt][r];
      }
  }
  __syncthreads();

  for (int o = t; o < GN * X3; o += 256) {
    int g = o / X3, rem = o - g * X3, c = rem / 3;
    float s = 0.f;
    #pragma unroll
    for (int k = 0; k < Kc; ++k) {
      int e = g * Kc + k;
      s += b2fu(s_xd[e * 44 + rem]) * s_coef[(e << 4) + c];
    }
    int gn = n0 + g;
    Xout[(size_t)gn * X3 + rem] =
        Xin[(size_t)gn * X3 + rem] + s * s_cw[g * Cc + c] * (1.0f / 9.0f);
  }
}

// ---------------------------------------------------------------------------
extern "C" void kernel_launch(void* const* d_in, const int* in_sizes, int n_in,
                              void* d_out, int out_size, void* d_ws, size_t ws_size,
                              hipStream_t stream) {
  const float* X    = (const float*)d_in[0];
  const int*   S    = (const int*)d_in[1];
  const float* Etab = (const float*)d_in[2];
  const float* Wch  = (const float*)d_in[3];
  const float* Win  = (const float*)d_in[4];
  const float* Wr   = (const float*)d_in[5];
  const float* We1  = (const float*)d_in[6];
  const float* be1  = (const float*)d_in[7];
  const float* We2  = (const float*)d_in[8];
  const float* Wx1  = (const float*)d_in[9];
  const float* Wx2  = (const float*)d_in[10];
  const float* Wh1  = (const float*)d_in[11];
  const float* Wh2  = (const float*)d_in[12];
  const float* Wf1  = (const float*)d_in[13];
  const float* Wf2  = (const float*)d_in[14];
  (void)in_sizes; (void)n_in; (void)out_size; (void)ws_size;

  char* base = (char*)d_ws;
  size_t off = 0;
  auto alloc = [&](size_t bytes) {
    void* p = base + off;
    off += (bytes + 255) & ~(size_t)255;
    return p;
  };
  int*   nbr   = (int*)  alloc((size_t)Nn * Kc * 4);
  float* Htab  = (float*)alloc(NCLS * HID * 4);
  float* cwtab = (float*)alloc(NCLS * Cc * 4);
  float* Wrpf  = (float*)alloc((size_t)NL * CC * HID * 4);
  float* posG  = (float*)alloc((size_t)Bc * 3 * PSTR * 4);
  float* Xa    = (float*)alloc((size_t)Nn * X3 * 4);
  float* Xb    = (float*)alloc((size_t)Nn * X3 * 4);
  float* hv    = (float*)alloc((size_t)Nn * HID * 4);
  bf16*  hAv   = (bf16*) alloc((size_t)Nn * HID * 2);
  bf16*  hBv   = (bf16*) alloc((size_t)Nn * HID * 2);
  bf16*  aggmv = (bf16*) alloc((size_t)Nn * HID * 2);
  constexpr int WRP_SZ = 7 * 8 * 512;
  constexpr int W128_SZ = 4 * 8 * 512;
  constexpr int WX2_SZ = 4 * 1 * 512;
  constexpr int WH1_SZ = 8 * 8 * 512;
  constexpr int WF2_SZ = 4 * 2 * 512;
  unsigned short* Wrp_s  = (unsigned short*)alloc((size_t)NL * WRP_SZ * 2);
  unsigned short* We2_s  = (unsigned short*)alloc((size_t)NL * W128_SZ * 2);
  unsigned short* Wx1_s  = (unsigned short*)alloc((size_t)NL * W128_SZ * 2);
  unsigned short* Wx2_s  = (unsigned short*)alloc((size_t)NL * WX2_SZ * 2);
  unsigned short* Wh1_s  = (unsigned short*)alloc((size_t)NL * WH1_SZ * 2);
  unsigned short* Wh2_s  = (unsigned short*)alloc((size_t)NL * W128_SZ * 2);
  unsigned short* We1a_s = (unsigned short*)alloc((size_t)NL * W128_SZ * 2);
  unsigned short* We1b_s = (unsigned short*)alloc((size_t)NL * W128_SZ * 2);
  unsigned short* Wf1_s  = (unsigned short*)alloc(W128_SZ * 2);
  unsigned short* Wf2_s  = (unsigned short*)alloc(WF2_SZ * 2);

  wrp_kernel<<<NL * CC, 128, 0, stream>>>(Wr, We1, Wrpf);
  htab_kernel<<<NCLS, 128, 0, stream>>>(Etab, Win, Wch, Htab, cwtab);
  posx_kernel<<<79, 256, 0, stream>>>(X, posG);
  knn_kernel<<<Bc * ((Lc + KR2 - 1) / KR2), 256, 0, stream>>>(posG, nbr);

  ShufArgs sa;
  for (int l = 0; l < NL; ++l) {
    int e = l * 8;
    sa.src[e+0] = Wrpf + (size_t)l * CC * HID;       sa.dst[e+0] = Wrp_s  + (size_t)l * WRP_SZ;
    sa.K[e+0] = CC;  sa.N[e+0] = HID; sa.KT[e+0] = 7; sa.NT[e+0] = 8;
    sa.src[e+1] = We2 + (size_t)l * HID * HID;       sa.dst[e+1] = We2_s  + (size_t)l * W128_SZ;
    sa.K[e+1] = HID; sa.N[e+1] = HID; sa.KT[e+1] = 4; sa.NT[e+1] = 8;
    sa.src[e+2] = Wx1 + (size_t)l * HID * HID;       sa.dst[e+2] = Wx1_s  + (size_t)l * W128_SZ;
    sa.K[e+2] = HID; sa.N[e+2] = HID; sa.KT[e+2] = 4; sa.NT[e+2] = 8;
    sa.src[e+3] = Wx2 + (size_t)l * HID * Cc;        sa.dst[e+3] = Wx2_s  + (size_t)l * WX2_SZ;
    sa.K[e+3] = HID; sa.N[e+3] = Cc;  sa.KT[e+3] = 4; sa.NT[e+3] = 1;
    sa.src[e+4] = Wh1 + (size_t)l * 256 * HID;       sa.dst[e+4] = Wh1_s  + (size_t)l * WH1_SZ;
    sa.K[e+4] = 256; sa.N[e+4] = HID; sa.KT[e+4] = 8; sa.NT[e+4] = 8;
    sa.src[e+5] = Wh2 + (size_t)l * HID * HID;       sa.dst[e+5] = Wh2_s  + (size_t)l * W128_SZ;
    sa.K[e+5] = HID; sa.N[e+5] = HID; sa.KT[e+5] = 4; sa.NT[e+5] = 8;
    sa.src[e+6] = We1 + (size_t)l * 384 * HID;       sa.dst[e+6] = We1a_s + (size_t)l * W128_SZ;
    sa.K[e+6] = HID; sa.N[e+6] = HID; sa.KT[e+6] = 4; sa.NT[e+6] = 8;
    sa.src[e+7] = We1 + (size_t)l * 384 * HID + (size_t)HID * HID;
    sa.dst[e+7] = We1b_s + (size_t)l * W128_SZ;
    sa.K[e+7] = HID; sa.N[e+7] = HID; sa.KT[e+7] = 4; sa.NT[e+7] = 8;
  }
  sa.src[24] = Wf1; sa.dst[24] = Wf1_s; sa.K[24] = HID; sa.N[24] = HID;
  sa.KT[24] = 4; sa.NT[24] = 8;
  sa.src[25] = Wf2; sa.dst[25] = Wf2_s; sa.K[25] = HID; sa.N[25] = NCLS;
  sa.KT[25] = 4; sa.NT[25] = 2;
  shufb_kernel<<<dim3(16, NSH), 256, 0, stream>>>(sa);

  nodeABm_kernel<<<Nn / 16, 256, 0, stream>>>(S, Htab, hv, We1a_s, We1b_s, be1,
                                              hAv, hBv);

  float* out = (float*)d_out;
  float* outX = out + (size_t)Nn * NCLS;
  const float* Xi = X;
  for (int l = 0; l < NL; ++l) {
    float* Xo = (l == NL - 1) ? outX : ((l == 0) ? Xb : Xa);
    edge_kernel<<<Nn / GN, 256, 0, stream>>>(
        Xi, Xo, hAv, hBv, S, cwtab, nbr,
        Wrp_s + (size_t)l * WRP_SZ, We2_s + (size_t)l * W128_SZ,
        Wx1_s + (size_t)l * W128_SZ, Wx2_s + (size_t)l * WX2_SZ, aggmv);
    if (l < NL - 1) {
      fupdAB_kernel<<<Nn / 16, 256, 0, stream>>>(
          hv, aggmv, Wh1_s + (size_t)l * WH1_SZ, Wh2_s + (size_t)l * W128_SZ,
          We1a_s + (size_t)(l + 1) * W128_SZ, We1b_s + (size_t)(l + 1) * W128_SZ,
          be1 + (l + 1) * HID, hAv, hBv);
    } else {
      fupdF_kernel<<<Nn / 16, 256, 0, stream>>>(
          hv, aggmv, Wh1_s + (size_t)l * WH1_SZ, Wh2_s + (size_t)l * W128_SZ,
          Wf1_s, Wf2_s, out);
    }
    Xi = Xo;
  }
}